// Round 1
// baseline (2064.299 us; speedup 1.0000x reference)
//
#include <hip/hip_runtime.h>
#include <hip/hip_bf16.h>
#include <math.h>

// SurfaceAbstraction: gather(32 nbrs) -> [relcoord|sphere|normal|feat] (73)
// -> 3x (1x1 conv + global-batch BN + relu) -> max over neighbors.
// Strategy: BN needs global per-channel stats => 3 stats passes (recompute)
// + tiny finalize. Never materialize (N,32,C): maxpool commutes with the
// monotone BN+relu, so only per-point max/min of raw y2 are stored.
// lane = sample, wave = channel slice; weights via readfirstlane-uniform
// pointers => s_load (scalar cache), x via LDS with odd strides (2-way only).

constexpr int NS = 32;
constexpr int GRID_STATS = 1024;
constexpr float BN_EPS = 1e-5f;
constexpr float INV_PI  = 0.31830988618379067f;
constexpr float INV_2PI = 0.15915494309189535f;

template <int STAGE>
__global__ __launch_bounds__(256) void stage_kernel(
    const float* __restrict__ center, const float* __restrict__ normal,
    const float* __restrict__ feature, const int* __restrict__ gidx,
    const float* __restrict__ w0, const float* __restrict__ b0,
    const float* __restrict__ w1, const float* __restrict__ b1,
    const float* __restrict__ w2, const float* __restrict__ b2,
    const float* __restrict__ g0, const float* __restrict__ be0,
    const float* __restrict__ g1, const float* __restrict__ be1,
    const float* __restrict__ fstats, float* __restrict__ part,
    float* __restrict__ ymax, float* __restrict__ ymin,
    int ntiles, float inv_cnt)
{
    __shared__ float Xs[64 * 77];    // 73-dim input, stride 77 (odd)
    __shared__ float X1s[64 * 65];   // 64-dim, stride 65 (odd)
    __shared__ float a0s[64], c0s[64], a1s[64], c1s[64];

    const int t = threadIdx.x;
    const int lane = t & 63;
    const int wvu = __builtin_amdgcn_readfirstlane(t >> 6);  // wave id 0..3

    if (STAGE >= 1 && t < 64) {
        float mean = fstats[t] * inv_cnt;
        float var  = fstats[64 + t] * inv_cnt - mean * mean;
        float a = g0[t] * rsqrtf(fmaxf(var, 0.f) + BN_EPS);
        a0s[t] = a; c0s[t] = be0[t] - a * mean;
    }
    if (STAGE >= 2 && t < 64) {
        float mean = fstats[128 + t] * inv_cnt;
        float var  = fstats[192 + t] * inv_cnt - mean * mean;
        float a = g1[t] * rsqrtf(fmaxf(var, 0.f) + BN_EPS);
        a1s[t] = a; c1s[t] = be1[t] - a * mean;
    }

    // wave-uniform weight bases -> scalar loads
    const float* w0r = w0 + wvu * 16 * 73;
    const float* b0r = b0 + wvu * 16;
    const float* w1r = w1 + wvu * 16 * 64;
    const float* b1r = b1 + wvu * 16;
    const float* w2r = w2 + wvu * 32 * 64;
    const float* b2r = b2 + wvu * 32;

    constexpr int NST = (STAGE == 2) ? 32 : 16;
    float ssum[NST], ssq[NST];
#pragma unroll
    for (int j = 0; j < NST; ++j) { ssum[j] = 0.f; ssq[j] = 0.f; }

    for (int tile = blockIdx.x; tile < ntiles; tile += gridDim.x) {
        const int m0 = tile * 2;           // 2 points (=64 samples) per tile
        __syncthreads();                   // protect LDS reuse across tiles
        {   // ---- gather: build X[64][73] ----
            const int s = lane;
            const int part4 = t >> 6;
            const int m = m0 + (s >> 5);
            const int n = s & 31;
            const int j = gidx[m * NS + n];
            if (part4 == 0) {
                float cmx = center[m*3+0], cmy = center[m*3+1], cmz = center[m*3+2];
                float gx = center[j*3+0]-cmx, gy = center[j*3+1]-cmy, gz = center[j*3+2]-cmz;
                float rho = sqrtf(gx*gx + gy*gy + gz*gz);
                float th = 0.f;
                if (rho > 0.f) {
                    float cz = fminf(1.f, fmaxf(-1.f, gz / rho));
                    th = acosf(cz) * INV_PI;
                }
                float ph = atan2f(gy, gx) * INV_2PI + 0.5f;
                float* xr = &Xs[s * 77];
                xr[0]=gx; xr[1]=gy; xr[2]=gz; xr[3]=rho; xr[4]=th; xr[5]=ph;
            } else if (part4 == 1) {
                Xs[s*77+6]=normal[j*3+0]; Xs[s*77+7]=normal[j*3+1]; Xs[s*77+8]=normal[j*3+2];
            }
            const float4* fp = (const float4*)(feature + (size_t)j * 64 + part4 * 16);
            float* xr = &Xs[s * 77 + 9 + part4 * 16];
#pragma unroll
            for (int q = 0; q < 4; ++q) {
                float4 v = fp[q];
                xr[q*4+0]=v.x; xr[q*4+1]=v.y; xr[q*4+2]=v.z; xr[q*4+3]=v.w;
            }
        }
        __syncthreads();
        // ---- conv0: 73 -> 64 (16 ch per wave) ----
        float acc[16];
#pragma unroll
        for (int j = 0; j < 16; ++j) acc[j] = b0r[j];
        for (int k = 0; k < 73; ++k) {
            float xv = Xs[lane * 77 + k];
#pragma unroll
            for (int j = 0; j < 16; ++j) acc[j] = fmaf(w0r[j*73 + k], xv, acc[j]);
        }
        if constexpr (STAGE == 0) {
#pragma unroll
            for (int j = 0; j < 16; ++j) { ssum[j] += acc[j]; ssq[j] += acc[j]*acc[j]; }
        } else {
#pragma unroll
            for (int j = 0; j < 16; ++j) {
                int c = wvu * 16 + j;
                X1s[lane * 65 + c] = fmaxf(a0s[c] * acc[j] + c0s[c], 0.f);
            }
            __syncthreads();
            // ---- conv1: 64 -> 64 ----
            float acc1[16];
#pragma unroll
            for (int j = 0; j < 16; ++j) acc1[j] = b1r[j];
            for (int k = 0; k < 64; ++k) {
                float xv = X1s[lane * 65 + k];
#pragma unroll
                for (int j = 0; j < 16; ++j) acc1[j] = fmaf(w1r[j*64 + k], xv, acc1[j]);
            }
            if constexpr (STAGE == 1) {
#pragma unroll
                for (int j = 0; j < 16; ++j) { ssum[j] += acc1[j]; ssq[j] += acc1[j]*acc1[j]; }
            } else {
                float* X2s = Xs;  // reuse Xs buffer as [64][65]
#pragma unroll
                for (int j = 0; j < 16; ++j) {
                    int c = wvu * 16 + j;
                    X2s[lane * 65 + c] = fmaxf(a1s[c] * acc1[j] + c1s[c], 0.f);
                }
                __syncthreads();
                // ---- conv2: 64 -> 128 (32 ch per wave) ----
                float acc2[32];
#pragma unroll
                for (int j = 0; j < 32; ++j) acc2[j] = b2r[j];
                for (int k = 0; k < 64; ++k) {
                    float xv = X2s[lane * 65 + k];
#pragma unroll
                    for (int j = 0; j < 32; ++j) acc2[j] = fmaf(w2r[j*64 + k], xv, acc2[j]);
                }
#pragma unroll
                for (int j = 0; j < 32; ++j) { ssum[j] += acc2[j]; ssq[j] += acc2[j]*acc2[j]; }
                // per-point max/min of raw y2 over the 32 neighbors
#pragma unroll
                for (int j = 0; j < 32; ++j) {
                    float mx = acc2[j], mn = acc2[j];
#pragma unroll
                    for (int msk = 1; msk <= 16; msk <<= 1) {
                        mx = fmaxf(mx, __shfl_xor(mx, msk, 64));
                        mn = fminf(mn, __shfl_xor(mn, msk, 64));
                    }
                    if ((lane & 31) == 0) {
                        int m = m0 + (lane >> 5);
                        int c = wvu * 32 + j;
                        ymax[(size_t)m * 128 + c] = mx;
                        ymin[(size_t)m * 128 + c] = mn;
                    }
                }
            }
        }
    }

    // ---- deterministic per-block partials ----
    float* pb = part + (size_t)blockIdx.x * 256;
#pragma unroll
    for (int j = 0; j < NST; ++j) {
        float v = ssum[j], q = ssq[j];
#pragma unroll
        for (int msk = 1; msk <= 32; msk <<= 1) {
            v += __shfl_xor(v, msk, 64);
            q += __shfl_xor(q, msk, 64);
        }
        if (lane == 0) {
            if (STAGE == 2) { pb[wvu*32 + j] = v; pb[128 + wvu*32 + j] = q; }
            else            { pb[wvu*16 + j] = v; pb[64  + wvu*16 + j] = q; }
        }
    }
}

// one block per output column; deterministic tree reduce over blocks
__global__ __launch_bounds__(256) void reduce_partials(
    const float* __restrict__ part, float* __restrict__ fstats,
    int base, int nblocks)
{
    __shared__ float red[256];
    int c = blockIdx.x;
    float s = 0.f;
    for (int b = threadIdx.x; b < nblocks; b += 256)
        s += part[(size_t)b * 256 + c];
    red[threadIdx.x] = s;
    __syncthreads();
    for (int off = 128; off > 0; off >>= 1) {
        if (threadIdx.x < off) red[threadIdx.x] += red[threadIdx.x + off];
        __syncthreads();
    }
    if (threadIdx.x == 0) fstats[base + c] = red[0];
}

__global__ __launch_bounds__(256) void final_kernel(
    const float* __restrict__ center, const float* __restrict__ normal,
    const int* __restrict__ offs,
    const float* __restrict__ g2, const float* __restrict__ be2,
    const float* __restrict__ fstats,
    const float* __restrict__ ymax, const float* __restrict__ ymin,
    float* __restrict__ out, int N, float inv_cnt)
{
    int i = blockIdx.x * 256 + threadIdx.x;
    int nc = N * 3;
    int nf = N * 128;
    int total = 2 * nc + nf + 1;
    if (i >= total) return;
    if (i < nc) {
        out[i] = center[i];
    } else if (i < 2 * nc) {
        out[i] = normal[i - nc];
    } else if (i < 2 * nc + nf) {
        int idx = i - 2 * nc;
        int c = idx & 127;
        float mean = fstats[256 + c] * inv_cnt;
        float var  = fstats[384 + c] * inv_cnt - mean * mean;
        float a = g2[c] * rsqrtf(fmaxf(var, 0.f) + BN_EPS);
        float v = (a >= 0.f) ? ymax[idx] : ymin[idx];   // monotone BN+relu
        out[i] = fmaxf(a * (v - mean) + be2[c], 0.f);
    } else {
        out[i] = (float)offs[0];
    }
}

extern "C" void kernel_launch(void* const* d_in, const int* in_sizes, int n_in,
                              void* d_out, int out_size, void* d_ws, size_t ws_size,
                              hipStream_t stream)
{
    const float* center  = (const float*)d_in[0];
    const float* normal  = (const float*)d_in[1];
    const float* feature = (const float*)d_in[2];
    const int*   offs    = (const int*)d_in[3];
    const int*   gidx    = (const int*)d_in[4];
    const float* w0  = (const float*)d_in[5];
    const float* b0  = (const float*)d_in[6];
    const float* g0  = (const float*)d_in[7];
    const float* be0 = (const float*)d_in[8];
    const float* w1  = (const float*)d_in[9];
    const float* b1  = (const float*)d_in[10];
    const float* g1  = (const float*)d_in[11];
    const float* be1 = (const float*)d_in[12];
    const float* w2  = (const float*)d_in[13];
    const float* b2  = (const float*)d_in[14];
    const float* g2  = (const float*)d_in[15];
    const float* be2 = (const float*)d_in[16];

    const int N = in_sizes[0] / 3;
    const int ntiles = N / 2;
    const float inv_cnt = 1.0f / (float)((size_t)N * NS);

    float* out = (float*)d_out;
    float* out_nf = out + (size_t)2 * N * 3;     // ymax lives here in-place

    float* wsf    = (float*)d_ws;
    float* fstats = wsf;                          // [512]
    float* part   = wsf + 512;                    // [GRID_STATS*256]
    float* ymin   = wsf + 512 + (size_t)GRID_STATS * 256;  // [N*128]

    dim3 blk(256), grd(GRID_STATS);

    stage_kernel<0><<<grd, blk, 0, stream>>>(center, normal, feature, gidx,
        w0, b0, w1, b1, w2, b2, g0, be0, g1, be1,
        fstats, part, out_nf, ymin, ntiles, inv_cnt);
    reduce_partials<<<dim3(128), blk, 0, stream>>>(part, fstats, 0, GRID_STATS);

    stage_kernel<1><<<grd, blk, 0, stream>>>(center, normal, feature, gidx,
        w0, b0, w1, b1, w2, b2, g0, be0, g1, be1,
        fstats, part, out_nf, ymin, ntiles, inv_cnt);
    reduce_partials<<<dim3(128), blk, 0, stream>>>(part, fstats, 128, GRID_STATS);

    stage_kernel<2><<<grd, blk, 0, stream>>>(center, normal, feature, gidx,
        w0, b0, w1, b1, w2, b2, g0, be0, g1, be1,
        fstats, part, out_nf, ymin, ntiles, inv_cnt);
    reduce_partials<<<dim3(256), blk, 0, stream>>>(part, fstats, 256, GRID_STATS);

    int total = 2 * N * 3 + N * 128 + 1;
    final_kernel<<<dim3((total + 255) / 256), blk, 0, stream>>>(
        center, normal, offs, g2, be2, fstats, out_nf, ymin, out, N, inv_cnt);
}

// Round 2
// 1005.714 us; speedup vs baseline: 2.0526x; 2.0526x over previous
//
#include <hip/hip_runtime.h>
#include <hip/hip_bf16.h>
#include <math.h>

// SurfaceAbstraction: gather(32 nbrs) -> [relcoord|sphere|normal|feat](73)
// -> 3x (1x1 conv + global-batch BN + relu) -> max over neighbors.
// BN needs global stats => 3 recompute passes + finalize. Maxpool commutes
// with monotone BN+relu => store per-point max/min of raw y2 only.
//
// R2 changes (theory: latency-stalled, VALUBusy 25%):
//  - weights pre-transposed to k-major => one s_load_dwordx16 per k
//  - 2 samples/lane ([lane][k][2] LDS layout, ds_read_b64 feeds 32 FMAs)
//  - maxpool reduction via DPP (VALU pipe) instead of __shfl_xor (LDS pipe)
//  - single in-place LDS buffer (stride 150) => 39.4KB/block, 4 blocks/CU

constexpr int NS = 32;
constexpr int GRID_STATS = 1024;
constexpr float BN_EPS = 1e-5f;
constexpr float INV_PI  = 0.31830988618379067f;
constexpr float INV_2PI = 0.15915494309189535f;

constexpr int XSTR = 150;  // words per row; 75 odd*2 => even b64 bank spread

// ---- DPP 32-lane max/min reduce, result in lanes 31 and 63 ----
template <int CTRL>
__device__ __forceinline__ float dpp_mov(float x) {
    return __int_as_float(__builtin_amdgcn_update_dpp(
        __float_as_int(x), __float_as_int(x), CTRL, 0xF, 0xF, false));
}
__device__ __forceinline__ void red32(float& mx, float& mn) {
    float p;
    p = dpp_mov<0x111>(mx); mx = fmaxf(mx, p);   // row_shr:1
    p = dpp_mov<0x112>(mx); mx = fmaxf(mx, p);   // row_shr:2
    p = dpp_mov<0x114>(mx); mx = fmaxf(mx, p);   // row_shr:4
    p = dpp_mov<0x118>(mx); mx = fmaxf(mx, p);   // row_shr:8
    p = dpp_mov<0x142>(mx); mx = fmaxf(mx, p);   // row_bcast:15
    p = dpp_mov<0x111>(mn); mn = fminf(mn, p);
    p = dpp_mov<0x112>(mn); mn = fminf(mn, p);
    p = dpp_mov<0x114>(mn); mn = fminf(mn, p);
    p = dpp_mov<0x118>(mn); mn = fminf(mn, p);
    p = dpp_mov<0x142>(mn); mn = fminf(mn, p);
}

// transpose weights to k-major: wt[k][c]
__global__ __launch_bounds__(256) void prep_weights(
    const float* __restrict__ w0, const float* __restrict__ w1,
    const float* __restrict__ w2, float* __restrict__ wt0,
    float* __restrict__ wt1, float* __restrict__ wt2)
{
    int i = blockIdx.x * 256 + threadIdx.x;
    if (i < 73 * 64) {
        int k = i >> 6, c = i & 63;
        wt0[i] = w0[c * 73 + k];
    } else if (i < 73 * 64 + 64 * 64) {
        int r = i - 73 * 64;
        int k = r >> 6, c = r & 63;
        wt1[r] = w1[c * 64 + k];
    } else if (i < 73 * 64 + 64 * 64 + 64 * 128) {
        int r = i - 73 * 64 - 64 * 64;
        int k = r >> 7, c = r & 127;
        wt2[r] = w2[c * 64 + k];
    }
}

template <int STAGE>
__global__ __launch_bounds__(256) void stage_kernel(
    const float* __restrict__ center, const float* __restrict__ normal,
    const float* __restrict__ feature, const int* __restrict__ gidx,
    const float* __restrict__ wt0, const float* __restrict__ b0,
    const float* __restrict__ wt1, const float* __restrict__ b1,
    const float* __restrict__ wt2, const float* __restrict__ b2,
    const float* __restrict__ g0, const float* __restrict__ be0,
    const float* __restrict__ g1, const float* __restrict__ be1,
    const float* __restrict__ fstats, float* __restrict__ part,
    float* __restrict__ ymax, float* __restrict__ ymin,
    int ntiles, float inv_cnt)
{
    __shared__ float Xs[64 * XSTR];            // [row][k][slot] in-place all layers
    __shared__ float a0s[64], c0s[64], a1s[64], c1s[64];

    const int t = threadIdx.x;
    const int lane = t & 63;
    const int wvu = __builtin_amdgcn_readfirstlane(t >> 6);  // wave id 0..3

    if (STAGE >= 1 && t < 64) {
        float mean = fstats[t] * inv_cnt;
        float var  = fstats[64 + t] * inv_cnt - mean * mean;
        float a = g0[t] * rsqrtf(fmaxf(var, 0.f) + BN_EPS);
        a0s[t] = a; c0s[t] = be0[t] - a * mean;
    }
    if (STAGE >= 2 && t < 64) {
        float mean = fstats[128 + t] * inv_cnt;
        float var  = fstats[192 + t] * inv_cnt - mean * mean;
        float a = g1[t] * rsqrtf(fmaxf(var, 0.f) + BN_EPS);
        a1s[t] = a; c1s[t] = be1[t] - a * mean;
    }

    constexpr int NST = (STAGE == 2) ? 32 : 16;
    float ssum[NST], ssq[NST];
#pragma unroll
    for (int j = 0; j < NST; ++j) { ssum[j] = 0.f; ssq[j] = 0.f; }

    const float* b0r = b0 + wvu * 16;
    const float* b1r = b1 + wvu * 16;
    const float* b2r = b2 + wvu * 32;

    for (int tile = blockIdx.x; tile < ntiles; tile += gridDim.x) {
        const int m0 = tile * 4;               // 4 points = 128 samples per tile
        __syncthreads();                       // protect Xs reuse across tiles
        {   // ---- gather: 128 samples x 73 dims, 2 threads per sample ----
            const int s    = t & 127;
            const int half = t >> 7;
            const int row  = s & 63;
            const int slot = s >> 6;
            const int m    = m0 + (s >> 5);
            const int j    = gidx[m * NS + (s & 31)];
            float* xr = &Xs[row * XSTR + slot];
            if (half == 0) {
                float cmx = center[m*3+0], cmy = center[m*3+1], cmz = center[m*3+2];
                float gx = center[j*3+0]-cmx, gy = center[j*3+1]-cmy, gz = center[j*3+2]-cmz;
                float rho = sqrtf(gx*gx + gy*gy + gz*gz);
                float th = 0.f;
                if (rho > 0.f) {
                    float cz = fminf(1.f, fmaxf(-1.f, gz / rho));
                    th = acosf(cz) * INV_PI;
                }
                float ph = atan2f(gy, gx) * INV_2PI + 0.5f;
                xr[0*2]=gx; xr[1*2]=gy; xr[2*2]=gz; xr[3*2]=rho; xr[4*2]=th; xr[5*2]=ph;
            } else {
                xr[6*2]=normal[j*3+0]; xr[7*2]=normal[j*3+1]; xr[8*2]=normal[j*3+2];
            }
            const float4* fp = (const float4*)(feature + (size_t)j * 64 + half * 32);
#pragma unroll
            for (int q = 0; q < 8; ++q) {
                float4 v = fp[q];
                int kb = 9 + half * 32 + q * 4;
                xr[(kb+0)*2]=v.x; xr[(kb+1)*2]=v.y; xr[(kb+2)*2]=v.z; xr[(kb+3)*2]=v.w;
            }
        }
        __syncthreads();
        // ---- conv0: 73 -> 64, 16 ch/wave, 2 samples/lane ----
        float ac0[16], ac1[16];
#pragma unroll
        for (int j = 0; j < 16; ++j) { float b = b0r[j]; ac0[j] = b; ac1[j] = b; }
#pragma unroll 4
        for (int k = 0; k < 73; ++k) {
            float2 xv = *(const float2*)&Xs[lane * XSTR + 2 * k];
            const float* wk = wt0 + k * 64 + wvu * 16;   // uniform -> s_load_x16
#pragma unroll
            for (int j = 0; j < 16; ++j) {
                float w = wk[j];
                ac0[j] = fmaf(w, xv.x, ac0[j]);
                ac1[j] = fmaf(w, xv.y, ac1[j]);
            }
        }
        if constexpr (STAGE == 0) {
#pragma unroll
            for (int j = 0; j < 16; ++j) {
                ssum[j] += ac0[j] + ac1[j];
                ssq[j]  += ac0[j]*ac0[j] + ac1[j]*ac1[j];
            }
        } else {
            __syncthreads();                   // all conv0 reads of Xs done
#pragma unroll
            for (int j = 0; j < 16; ++j) {     // X1 -> Xs in place
                int c = wvu * 16 + j;
                float a = a0s[c], cc = c0s[c];
                float2 v;
                v.x = fmaxf(a * ac0[j] + cc, 0.f);
                v.y = fmaxf(a * ac1[j] + cc, 0.f);
                *(float2*)&Xs[lane * XSTR + 2 * c] = v;
            }
            __syncthreads();
            // ---- conv1: 64 -> 64 ----
            float bc0[16], bc1[16];
#pragma unroll
            for (int j = 0; j < 16; ++j) { float b = b1r[j]; bc0[j] = b; bc1[j] = b; }
#pragma unroll 4
            for (int k = 0; k < 64; ++k) {
                float2 xv = *(const float2*)&Xs[lane * XSTR + 2 * k];
                const float* wk = wt1 + k * 64 + wvu * 16;
#pragma unroll
                for (int j = 0; j < 16; ++j) {
                    float w = wk[j];
                    bc0[j] = fmaf(w, xv.x, bc0[j]);
                    bc1[j] = fmaf(w, xv.y, bc1[j]);
                }
            }
            if constexpr (STAGE == 1) {
#pragma unroll
                for (int j = 0; j < 16; ++j) {
                    ssum[j] += bc0[j] + bc1[j];
                    ssq[j]  += bc0[j]*bc0[j] + bc1[j]*bc1[j];
                }
            } else {
                __syncthreads();
#pragma unroll
                for (int j = 0; j < 16; ++j) { // X2 -> Xs in place
                    int c = wvu * 16 + j;
                    float a = a1s[c], cc = c1s[c];
                    float2 v;
                    v.x = fmaxf(a * bc0[j] + cc, 0.f);
                    v.y = fmaxf(a * bc1[j] + cc, 0.f);
                    *(float2*)&Xs[lane * XSTR + 2 * c] = v;
                }
                __syncthreads();
                // ---- conv2: 64 -> 128, 32 ch/wave ----
                float cc0[32], cc1[32];
#pragma unroll
                for (int j = 0; j < 32; ++j) { float b = b2r[j]; cc0[j] = b; cc1[j] = b; }
#pragma unroll 2
                for (int k = 0; k < 64; ++k) {
                    float2 xv = *(const float2*)&Xs[lane * XSTR + 2 * k];
                    const float* wk = wt2 + k * 128 + wvu * 32;
#pragma unroll
                    for (int j = 0; j < 32; ++j) {
                        float w = wk[j];
                        cc0[j] = fmaf(w, xv.x, cc0[j]);
                        cc1[j] = fmaf(w, xv.y, cc1[j]);
                    }
                }
#pragma unroll
                for (int j = 0; j < 32; ++j) {
                    ssum[j] += cc0[j] + cc1[j];
                    ssq[j]  += cc0[j]*cc0[j] + cc1[j]*cc1[j];
                }
                // maxpool over 32 lanes per slot via DPP; result lanes 31/63
#pragma unroll
                for (int j = 0; j < 32; ++j) {
                    float mx0 = cc0[j], mn0 = cc0[j];
                    red32(mx0, mn0);
                    float mx1 = cc1[j], mn1 = cc1[j];
                    red32(mx1, mn1);
                    if ((lane & 31) == 31) {
                        int c = wvu * 32 + j;
                        size_t ma = (size_t)(m0 + (lane >> 5)) * 128 + c;      // slot 0
                        size_t mb = (size_t)(m0 + (lane >> 5) + 2) * 128 + c;  // slot 1
                        ymax[ma] = mx0; ymin[ma] = mn0;
                        ymax[mb] = mx1; ymin[mb] = mn1;
                    }
                }
            }
        }
    }

    // ---- deterministic per-block stats partials ----
    float* pb = part + (size_t)blockIdx.x * 256;
#pragma unroll
    for (int j = 0; j < NST; ++j) {
        float v = ssum[j], q = ssq[j];
#pragma unroll
        for (int msk = 1; msk <= 32; msk <<= 1) {
            v += __shfl_xor(v, msk, 64);
            q += __shfl_xor(q, msk, 64);
        }
        if (lane == 0) {
            if (STAGE == 2) { pb[wvu*32 + j] = v; pb[128 + wvu*32 + j] = q; }
            else            { pb[wvu*16 + j] = v; pb[64  + wvu*16 + j] = q; }
        }
    }
}

__global__ __launch_bounds__(256) void reduce_partials(
    const float* __restrict__ part, float* __restrict__ fstats,
    int base, int nblocks)
{
    __shared__ float red[256];
    int c = blockIdx.x;
    float s = 0.f;
    for (int b = threadIdx.x; b < nblocks; b += 256)
        s += part[(size_t)b * 256 + c];
    red[threadIdx.x] = s;
    __syncthreads();
    for (int off = 128; off > 0; off >>= 1) {
        if (threadIdx.x < off) red[threadIdx.x] += red[threadIdx.x + off];
        __syncthreads();
    }
    if (threadIdx.x == 0) fstats[base + c] = red[0];
}

__global__ __launch_bounds__(256) void final_kernel(
    const float* __restrict__ center, const float* __restrict__ normal,
    const int* __restrict__ offs,
    const float* __restrict__ g2, const float* __restrict__ be2,
    const float* __restrict__ fstats,
    const float* __restrict__ ymax, const float* __restrict__ ymin,
    float* __restrict__ out, int N, float inv_cnt)
{
    int i = blockIdx.x * 256 + threadIdx.x;
    int nc = N * 3;
    int nf = N * 128;
    int total = 2 * nc + nf + 1;
    if (i >= total) return;
    if (i < nc) {
        out[i] = center[i];
    } else if (i < 2 * nc) {
        out[i] = normal[i - nc];
    } else if (i < 2 * nc + nf) {
        int idx = i - 2 * nc;
        int c = idx & 127;
        float mean = fstats[256 + c] * inv_cnt;
        float var  = fstats[384 + c] * inv_cnt - mean * mean;
        float a = g2[c] * rsqrtf(fmaxf(var, 0.f) + BN_EPS);
        float v = (a >= 0.f) ? ymax[idx] : ymin[idx];   // monotone BN+relu
        out[i] = fmaxf(a * (v - mean) + be2[c], 0.f);
    } else {
        out[i] = (float)offs[0];
    }
}

extern "C" void kernel_launch(void* const* d_in, const int* in_sizes, int n_in,
                              void* d_out, int out_size, void* d_ws, size_t ws_size,
                              hipStream_t stream)
{
    const float* center  = (const float*)d_in[0];
    const float* normal  = (const float*)d_in[1];
    const float* feature = (const float*)d_in[2];
    const int*   offs    = (const int*)d_in[3];
    const int*   gidx    = (const int*)d_in[4];
    const float* w0  = (const float*)d_in[5];
    const float* b0  = (const float*)d_in[6];
    const float* g0  = (const float*)d_in[7];
    const float* be0 = (const float*)d_in[8];
    const float* w1  = (const float*)d_in[9];
    const float* b1  = (const float*)d_in[10];
    const float* g1  = (const float*)d_in[11];
    const float* be1 = (const float*)d_in[12];
    const float* w2  = (const float*)d_in[13];
    const float* b2  = (const float*)d_in[14];
    const float* g2  = (const float*)d_in[15];
    const float* be2 = (const float*)d_in[16];

    const int N = in_sizes[0] / 3;
    const int ntiles = N / 4;
    const float inv_cnt = 1.0f / (float)((size_t)N * NS);

    float* out = (float*)d_out;
    float* out_nf = out + (size_t)2 * N * 3;         // ymax in-place

    float* wsf    = (float*)d_ws;
    float* fstats = wsf;                              // [512]
    float* part   = wsf + 512;                        // [GRID_STATS*256]
    float* ymin   = part + (size_t)GRID_STATS * 256;  // [N*128]
    float* wt0    = ymin + (size_t)N * 128;           // [73*64]
    float* wt1    = wt0 + 73 * 64;                    // [64*64]
    float* wt2    = wt1 + 64 * 64;                    // [64*128]

    dim3 blk(256), grd(GRID_STATS);

    prep_weights<<<dim3(67), blk, 0, stream>>>(w0, w1, w2, wt0, wt1, wt2);

    stage_kernel<0><<<grd, blk, 0, stream>>>(center, normal, feature, gidx,
        wt0, b0, wt1, b1, wt2, b2, g0, be0, g1, be1,
        fstats, part, out_nf, ymin, ntiles, inv_cnt);
    reduce_partials<<<dim3(128), blk, 0, stream>>>(part, fstats, 0, GRID_STATS);

    stage_kernel<1><<<grd, blk, 0, stream>>>(center, normal, feature, gidx,
        wt0, b0, wt1, b1, wt2, b2, g0, be0, g1, be1,
        fstats, part, out_nf, ymin, ntiles, inv_cnt);
    reduce_partials<<<dim3(128), blk, 0, stream>>>(part, fstats, 128, GRID_STATS);

    stage_kernel<2><<<grd, blk, 0, stream>>>(center, normal, feature, gidx,
        wt0, b0, wt1, b1, wt2, b2, g0, be0, g1, be1,
        fstats, part, out_nf, ymin, ntiles, inv_cnt);
    reduce_partials<<<dim3(256), blk, 0, stream>>>(part, fstats, 256, GRID_STATS);

    int total = 2 * N * 3 + N * 128 + 1;
    final_kernel<<<dim3((total + 255) / 256), blk, 0, stream>>>(
        center, normal, offs, g2, be2, fstats, out_nf, ymin, out, N, inv_cnt);
}

// Round 3
// 597.260 us; speedup vs baseline: 3.4563x; 1.6839x over previous
//
#include <hip/hip_runtime.h>
#include <hip/hip_bf16.h>
#include <math.h>

// SurfaceAbstraction: gather(32 nbrs) -> [feat(64)|gx,gy,gz,rho,th,ph,nx,ny,nz|pad](K=96 permuted)
// -> 3x (1x1 conv + global-batch BN + relu) -> max over neighbors.
// R3: convs on bf16 MFMA (16x16x32). Weights as hi+lo bf16 fragment pairs
// (fp32-accurate weights; only activation rounding remains). Tile = 4 points
// = 128 rows bf16 in LDS, XOR-swizzled 16B units; wave = 1 point (2 M-tiles).
// BN stats via C/D-layout (col=lane&15,row=(lane>>4)*4+reg) + shfl_xor(16,32).

typedef __attribute__((ext_vector_type(8))) short short8;
typedef __attribute__((ext_vector_type(4))) float f32x4;

constexpr int NS = 32;
constexpr int GRID_STATS = 1024;
constexpr float BN_EPS = 1e-5f;
constexpr float INV_PI  = 0.31830988618379067f;
constexpr float INV_2PI = 0.15915494309189535f;

__device__ __forceinline__ short cvt_bf16(float f) {
    unsigned u = __float_as_uint(f);
    u = (u + 0x7FFFu + ((u >> 16) & 1u)) >> 16;
    return (short)u;
}
__device__ __forceinline__ float bf16_to_f(short s) {
    return __uint_as_float(((unsigned)(unsigned short)s) << 16);
}

// Build weight fragments: frag(kt,nt), lane l holds W[n=nt*16+(l&15)][k=kt*32+(l>>4)*8+j]
// j=0..7 contiguous, as hi/lo bf16 split (w = hi + lo to ~fp32 precision).
// conv0 K permuted: knew<64 -> orig 9+knew (feat); 64..71 -> orig 0..7; 72 -> orig 8; else 0.
__global__ __launch_bounds__(256) void prep_weights(
    const float* __restrict__ w0, const float* __restrict__ w1,
    const float* __restrict__ w2,
    short* __restrict__ wf0h, short* __restrict__ wf0l,
    short* __restrict__ wf1h, short* __restrict__ wf1l,
    short* __restrict__ wf2h, short* __restrict__ wf2l)
{
    int i = blockIdx.x * 256 + threadIdx.x;
    int l = i & 63;
    int f = i >> 6;
    float vals[8];
    short *dh, *dl;
    if (f < 12) {                       // conv0: 3 kt x 4 nt
        int kt = f >> 2, nt = f & 3;
        int n = nt * 16 + (l & 15);
        int k0 = kt * 32 + (l >> 4) * 8;
        for (int j = 0; j < 8; ++j) {
            int kn = k0 + j;
            float v;
            if (kn < 64)      v = w0[n * 73 + 9 + kn];
            else if (kn < 72) v = w0[n * 73 + (kn - 64)];
            else if (kn == 72) v = w0[n * 73 + 8];
            else v = 0.f;
            vals[j] = v;
        }
        dh = wf0h + (size_t)f * 512 + l * 8;
        dl = wf0l + (size_t)f * 512 + l * 8;
    } else if (f < 20) {                // conv1: 2 kt x 4 nt
        int ff = f - 12;
        int kt = ff >> 2, nt = ff & 3;
        int n = nt * 16 + (l & 15);
        int k0 = kt * 32 + (l >> 4) * 8;
        for (int j = 0; j < 8; ++j) vals[j] = w1[n * 64 + k0 + j];
        dh = wf1h + (size_t)ff * 512 + l * 8;
        dl = wf1l + (size_t)ff * 512 + l * 8;
    } else if (f < 36) {                // conv2: 2 kt x 8 nt
        int ff = f - 20;
        int kt = ff >> 3, nt = ff & 7;
        int n = nt * 16 + (l & 15);
        int k0 = kt * 32 + (l >> 4) * 8;
        for (int j = 0; j < 8; ++j) vals[j] = w2[n * 64 + k0 + j];
        dh = wf2h + (size_t)ff * 512 + l * 8;
        dl = wf2l + (size_t)ff * 512 + l * 8;
    } else return;
    for (int j = 0; j < 8; ++j) {
        short h = cvt_bf16(vals[j]);
        dh[j] = h;
        dl[j] = cvt_bf16(vals[j] - bf16_to_f(h));
    }
}

template <int STAGE>
__global__ __launch_bounds__(256) void stage_kernel(
    const float* __restrict__ center, const float* __restrict__ normal,
    const float* __restrict__ feature, const int* __restrict__ gidx,
    const short* __restrict__ wf0h, const short* __restrict__ wf0l,
    const short* __restrict__ wf1h, const short* __restrict__ wf1l,
    const short* __restrict__ wf2h, const short* __restrict__ wf2l,
    const float* __restrict__ b0, const float* __restrict__ b1,
    const float* __restrict__ b2,
    const float* __restrict__ g0, const float* __restrict__ be0,
    const float* __restrict__ g1, const float* __restrict__ be1,
    const float* __restrict__ fstats, float* __restrict__ part,
    float* __restrict__ ymax, float* __restrict__ ymin,
    int ntiles, float inv_cnt)
{
    // 128 rows x 128 bf16 (16 units of 16B), XOR-swizzled: unit u of row r at u^(r&7)
    __shared__ __align__(16) short Xs[128 * 128];
    __shared__ float a0s[64], c0s[64], a1s[64], c1s[64];
    __shared__ float sredS[4][128], sredQ[4][128];

    const int t    = threadIdx.x;
    const int lane = t & 63;
    const int wv   = t >> 6;
    const int ln   = lane & 15;
    const int kg   = lane >> 4;
    const int rxa  = (ln & 7) * 8;     // A-read swizzle (row&7 == ln&7 for all M-tiles)

    if constexpr (STAGE >= 1) {
        if (t < 64) {
            float mean = fstats[t] * inv_cnt;
            float var  = fstats[64 + t] * inv_cnt - mean * mean;
            float a = g0[t] * rsqrtf(fmaxf(var, 0.f) + BN_EPS);
            a0s[t] = a; c0s[t] = be0[t] - a * mean;
        }
    }
    if constexpr (STAGE >= 2) {
        if (t < 64) {
            float mean = fstats[128 + t] * inv_cnt;
            float var  = fstats[192 + t] * inv_cnt - mean * mean;
            float a = g1[t] * rsqrtf(fmaxf(var, 0.f) + BN_EPS);
            a1s[t] = a; c1s[t] = be1[t] - a * mean;
        }
    }
    {   // zero logical units 10,11 (k 80..95) once; never overwritten after
        int r = t >> 1, u = 10 + (t & 1);
        short8 z; z[0]=0;z[1]=0;z[2]=0;z[3]=0;z[4]=0;z[5]=0;z[6]=0;z[7]=0;
        *(short8*)(Xs + r * 128 + ((u ^ (r & 7)) * 8)) = z;
    }

    constexpr int NT = (STAGE == 2) ? 8 : 4;
    float ssum[NT], ssq[NT];
#pragma unroll
    for (int nt = 0; nt < NT; ++nt) { ssum[nt] = 0.f; ssq[nt] = 0.f; }

    float bb0[4];
#pragma unroll
    for (int nt = 0; nt < 4; ++nt) bb0[nt] = b0[nt * 16 + ln];
    float bb1[4];
    if constexpr (STAGE >= 1) {
#pragma unroll
        for (int nt = 0; nt < 4; ++nt) bb1[nt] = b1[nt * 16 + ln];
    }
    float bb2[8];
    if constexpr (STAGE == 2) {
#pragma unroll
        for (int nt = 0; nt < 8; ++nt) bb2[nt] = b2[nt * 16 + ln];
    }

    const int rb = wv * 32;            // wave's point-rows base

    for (int tile = blockIdx.x; tile < ntiles; tile += gridDim.x) {
        const int m0 = tile * 4;
        __syncthreads();               // prior tile's LDS reads done
        {   // ---- gather: 128 samples, 2 threads/sample ----
            const int s = t & 127, h = t >> 7;
            const int m = m0 + (s >> 5);
            const int j = gidx[m * NS + (s & 31)];
            short* xr = Xs + s * 128;
            const int rx = (s & 7) * 8;
            const float4* fp = (const float4*)(feature + (size_t)j * 64 + h * 32);
#pragma unroll
            for (int q = 0; q < 4; ++q) {
                float4 a = fp[2 * q], b = fp[2 * q + 1];
                short8 v;
                v[0]=cvt_bf16(a.x); v[1]=cvt_bf16(a.y); v[2]=cvt_bf16(a.z); v[3]=cvt_bf16(a.w);
                v[4]=cvt_bf16(b.x); v[5]=cvt_bf16(b.y); v[6]=cvt_bf16(b.z); v[7]=cvt_bf16(b.w);
                *(short8*)(xr + ((((h * 4 + q) * 8)) ^ rx)) = v;
            }
            if (h == 0) {
                float gx = center[j*3+0] - center[m*3+0];
                float gy = center[j*3+1] - center[m*3+1];
                float gz = center[j*3+2] - center[m*3+2];
                float rho = sqrtf(gx*gx + gy*gy + gz*gz);
                float th = 0.f;
                if (rho > 0.f) th = acosf(fminf(1.f, fmaxf(-1.f, gz / rho))) * INV_PI;
                float ph = atan2f(gy, gx) * INV_2PI + 0.5f;
                short8 v;
                v[0]=cvt_bf16(gx);  v[1]=cvt_bf16(gy); v[2]=cvt_bf16(gz);
                v[3]=cvt_bf16(rho); v[4]=cvt_bf16(th); v[5]=cvt_bf16(ph);
                v[6]=cvt_bf16(normal[j*3+0]); v[7]=cvt_bf16(normal[j*3+1]);
                *(short8*)(xr + ((8 * 8) ^ rx)) = v;
            } else {
                short8 v; v[0]=cvt_bf16(normal[j*3+2]);
                v[1]=0;v[2]=0;v[3]=0;v[4]=0;v[5]=0;v[6]=0;v[7]=0;
                *(short8*)(xr + ((9 * 8) ^ rx)) = v;
            }
        }
        __syncthreads();
        // ---- conv0: K=96 (3 kt), N=64 (4 nt), M=32 (2 mt) ----
        f32x4 acc0[2][4];
#pragma unroll
        for (int nt = 0; nt < 4; ++nt) {
            f32x4 z; z[0]=bb0[nt]; z[1]=bb0[nt]; z[2]=bb0[nt]; z[3]=bb0[nt];
            acc0[0][nt] = z; acc0[1][nt] = z;
        }
#pragma unroll
        for (int kt = 0; kt < 3; ++kt) {
            short8 a0 = *(const short8*)(Xs + (rb + ln)      * 128 + ((((kt*4 + kg) * 8)) ^ rxa));
            short8 a1 = *(const short8*)(Xs + (rb + 16 + ln) * 128 + ((((kt*4 + kg) * 8)) ^ rxa));
#pragma unroll
            for (int nt = 0; nt < 4; ++nt) {
                short8 bh = *(const short8*)(wf0h + (size_t)((kt*4 + nt) * 64 + lane) * 8);
                short8 bl = *(const short8*)(wf0l + (size_t)((kt*4 + nt) * 64 + lane) * 8);
                acc0[0][nt] = __builtin_amdgcn_mfma_f32_16x16x32_bf16(a0, bh, acc0[0][nt], 0, 0, 0);
                acc0[0][nt] = __builtin_amdgcn_mfma_f32_16x16x32_bf16(a0, bl, acc0[0][nt], 0, 0, 0);
                acc0[1][nt] = __builtin_amdgcn_mfma_f32_16x16x32_bf16(a1, bh, acc0[1][nt], 0, 0, 0);
                acc0[1][nt] = __builtin_amdgcn_mfma_f32_16x16x32_bf16(a1, bl, acc0[1][nt], 0, 0, 0);
            }
        }
        if constexpr (STAGE == 0) {
#pragma unroll
            for (int nt = 0; nt < 4; ++nt)
#pragma unroll
                for (int mt = 0; mt < 2; ++mt)
#pragma unroll
                    for (int r = 0; r < 4; ++r) {
                        float y = acc0[mt][nt][r];
                        ssum[nt] += y; ssq[nt] += y * y;
                    }
        } else {
            __syncthreads();           // conv0 A-reads done before X1 overwrite
#pragma unroll
            for (int mt = 0; mt < 2; ++mt)
#pragma unroll
                for (int nt = 0; nt < 4; ++nt) {
                    int ch = nt * 16 + ln;
                    float a = a0s[ch], cc = c0s[ch];
#pragma unroll
                    for (int r = 0; r < 4; ++r) {
                        int row = rb + mt * 16 + kg * 4 + r;
                        float x1 = fmaxf(a * acc0[mt][nt][r] + cc, 0.f);
                        Xs[row * 128 + (ch ^ ((row & 7) * 8))] = cvt_bf16(x1);
                    }
                }
            __syncthreads();
            // ---- conv1: K=64 (2 kt), N=64 ----
            f32x4 acc1[2][4];
#pragma unroll
            for (int nt = 0; nt < 4; ++nt) {
                f32x4 z; z[0]=bb1[nt]; z[1]=bb1[nt]; z[2]=bb1[nt]; z[3]=bb1[nt];
                acc1[0][nt] = z; acc1[1][nt] = z;
            }
#pragma unroll
            for (int kt = 0; kt < 2; ++kt) {
                short8 a0 = *(const short8*)(Xs + (rb + ln)      * 128 + ((((kt*4 + kg) * 8)) ^ rxa));
                short8 a1 = *(const short8*)(Xs + (rb + 16 + ln) * 128 + ((((kt*4 + kg) * 8)) ^ rxa));
#pragma unroll
                for (int nt = 0; nt < 4; ++nt) {
                    short8 bh = *(const short8*)(wf1h + (size_t)((kt*4 + nt) * 64 + lane) * 8);
                    short8 bl = *(const short8*)(wf1l + (size_t)((kt*4 + nt) * 64 + lane) * 8);
                    acc1[0][nt] = __builtin_amdgcn_mfma_f32_16x16x32_bf16(a0, bh, acc1[0][nt], 0, 0, 0);
                    acc1[0][nt] = __builtin_amdgcn_mfma_f32_16x16x32_bf16(a0, bl, acc1[0][nt], 0, 0, 0);
                    acc1[1][nt] = __builtin_amdgcn_mfma_f32_16x16x32_bf16(a1, bh, acc1[1][nt], 0, 0, 0);
                    acc1[1][nt] = __builtin_amdgcn_mfma_f32_16x16x32_bf16(a1, bl, acc1[1][nt], 0, 0, 0);
                }
            }
            if constexpr (STAGE == 1) {
#pragma unroll
                for (int nt = 0; nt < 4; ++nt)
#pragma unroll
                    for (int mt = 0; mt < 2; ++mt)
#pragma unroll
                        for (int r = 0; r < 4; ++r) {
                            float y = acc1[mt][nt][r];
                            ssum[nt] += y; ssq[nt] += y * y;
                        }
            } else {
                __syncthreads();
#pragma unroll
                for (int mt = 0; mt < 2; ++mt)
#pragma unroll
                    for (int nt = 0; nt < 4; ++nt) {
                        int ch = nt * 16 + ln;
                        float a = a1s[ch], cc = c1s[ch];
#pragma unroll
                        for (int r = 0; r < 4; ++r) {
                            int row = rb + mt * 16 + kg * 4 + r;
                            float x2 = fmaxf(a * acc1[mt][nt][r] + cc, 0.f);
                            Xs[row * 128 + (ch ^ ((row & 7) * 8))] = cvt_bf16(x2);
                        }
                    }
                __syncthreads();
                // ---- conv2: K=64 (2 kt), N=128 (8 nt) ----
                f32x4 acc2[2][8];
#pragma unroll
                for (int nt = 0; nt < 8; ++nt) {
                    f32x4 z; z[0]=bb2[nt]; z[1]=bb2[nt]; z[2]=bb2[nt]; z[3]=bb2[nt];
                    acc2[0][nt] = z; acc2[1][nt] = z;
                }
#pragma unroll
                for (int kt = 0; kt < 2; ++kt) {
                    short8 a0 = *(const short8*)(Xs + (rb + ln)      * 128 + ((((kt*4 + kg) * 8)) ^ rxa));
                    short8 a1 = *(const short8*)(Xs + (rb + 16 + ln) * 128 + ((((kt*4 + kg) * 8)) ^ rxa));
#pragma unroll
                    for (int nt = 0; nt < 8; ++nt) {
                        short8 bh = *(const short8*)(wf2h + (size_t)((kt*8 + nt) * 64 + lane) * 8);
                        short8 bl = *(const short8*)(wf2l + (size_t)((kt*8 + nt) * 64 + lane) * 8);
                        acc2[0][nt] = __builtin_amdgcn_mfma_f32_16x16x32_bf16(a0, bh, acc2[0][nt], 0, 0, 0);
                        acc2[0][nt] = __builtin_amdgcn_mfma_f32_16x16x32_bf16(a0, bl, acc2[0][nt], 0, 0, 0);
                        acc2[1][nt] = __builtin_amdgcn_mfma_f32_16x16x32_bf16(a1, bh, acc2[1][nt], 0, 0, 0);
                        acc2[1][nt] = __builtin_amdgcn_mfma_f32_16x16x32_bf16(a1, bl, acc2[1][nt], 0, 0, 0);
                    }
                }
                // stats + maxpool over the wave's 32 rows (one point)
                const int p = m0 + wv;
#pragma unroll
                for (int nt = 0; nt < 8; ++nt) {
                    float mx = acc2[0][nt][0], mn = acc2[0][nt][0];
#pragma unroll
                    for (int mt = 0; mt < 2; ++mt)
#pragma unroll
                        for (int r = 0; r < 4; ++r) {
                            float y = acc2[mt][nt][r];
                            ssum[nt] += y; ssq[nt] += y * y;
                            mx = fmaxf(mx, y); mn = fminf(mn, y);
                        }
                    mx = fmaxf(mx, __shfl_xor(mx, 16)); mn = fminf(mn, __shfl_xor(mn, 16));
                    mx = fmaxf(mx, __shfl_xor(mx, 32)); mn = fminf(mn, __shfl_xor(mn, 32));
                    if (lane < 16) {
                        ymax[(size_t)p * 128 + nt * 16 + lane] = mx;
                        ymin[(size_t)p * 128 + nt * 16 + lane] = mn;
                    }
                }
            }
        }
    }

    // ---- stats epilogue: cross-lane, cross-wave, per-block partial ----
#pragma unroll
    for (int nt = 0; nt < NT; ++nt) {
        float v = ssum[nt], q = ssq[nt];
        v += __shfl_xor(v, 16); q += __shfl_xor(q, 16);
        v += __shfl_xor(v, 32); q += __shfl_xor(q, 32);
        if (lane < 16) { sredS[wv][nt * 16 + lane] = v; sredQ[wv][nt * 16 + lane] = q; }
    }
    __syncthreads();
    constexpr int NCH = NT * 16;
    float* pb = part + (size_t)blockIdx.x * 256;
    if (t < NCH) {
        pb[t] = sredS[0][t] + sredS[1][t] + sredS[2][t] + sredS[3][t];
    } else if (t < 2 * NCH) {
        int c = t - NCH;
        pb[NCH + c] = sredQ[0][c] + sredQ[1][c] + sredQ[2][c] + sredQ[3][c];
    }
}

__global__ __launch_bounds__(256) void reduce_partials(
    const float* __restrict__ part, float* __restrict__ fstats,
    int base, int nblocks)
{
    __shared__ float red[256];
    int c = blockIdx.x;
    float s = 0.f;
    for (int b = threadIdx.x; b < nblocks; b += 256)
        s += part[(size_t)b * 256 + c];
    red[threadIdx.x] = s;
    __syncthreads();
    for (int off = 128; off > 0; off >>= 1) {
        if (threadIdx.x < off) red[threadIdx.x] += red[threadIdx.x + off];
        __syncthreads();
    }
    if (threadIdx.x == 0) fstats[base + c] = red[0];
}

__global__ __launch_bounds__(256) void final_kernel(
    const float* __restrict__ center, const float* __restrict__ normal,
    const int* __restrict__ offs,
    const float* __restrict__ g2, const float* __restrict__ be2,
    const float* __restrict__ fstats,
    const float* __restrict__ ymax, const float* __restrict__ ymin,
    float* __restrict__ out, int N, float inv_cnt)
{
    int i = blockIdx.x * 256 + threadIdx.x;
    int nc = N * 3;
    int nf = N * 128;
    int total = 2 * nc + nf + 1;
    if (i >= total) return;
    if (i < nc) {
        out[i] = center[i];
    } else if (i < 2 * nc) {
        out[i] = normal[i - nc];
    } else if (i < 2 * nc + nf) {
        int idx = i - 2 * nc;
        int c = idx & 127;
        float mean = fstats[256 + c] * inv_cnt;
        float var  = fstats[384 + c] * inv_cnt - mean * mean;
        float a = g2[c] * rsqrtf(fmaxf(var, 0.f) + BN_EPS);
        float v = (a >= 0.f) ? ymax[idx] : ymin[idx];   // monotone BN+relu
        out[i] = fmaxf(a * (v - mean) + be2[c], 0.f);
    } else {
        out[i] = (float)offs[0];
    }
}

extern "C" void kernel_launch(void* const* d_in, const int* in_sizes, int n_in,
                              void* d_out, int out_size, void* d_ws, size_t ws_size,
                              hipStream_t stream)
{
    const float* center  = (const float*)d_in[0];
    const float* normal  = (const float*)d_in[1];
    const float* feature = (const float*)d_in[2];
    const int*   offs    = (const int*)d_in[3];
    const int*   gidx    = (const int*)d_in[4];
    const float* w0  = (const float*)d_in[5];
    const float* b0  = (const float*)d_in[6];
    const float* g0  = (const float*)d_in[7];
    const float* be0 = (const float*)d_in[8];
    const float* w1  = (const float*)d_in[9];
    const float* b1  = (const float*)d_in[10];
    const float* g1  = (const float*)d_in[11];
    const float* be1 = (const float*)d_in[12];
    const float* w2  = (const float*)d_in[13];
    const float* b2  = (const float*)d_in[14];
    const float* g2  = (const float*)d_in[15];
    const float* be2 = (const float*)d_in[16];

    const int N = in_sizes[0] / 3;
    const int ntiles = N / 4;
    const float inv_cnt = 1.0f / (float)((size_t)N * NS);

    float* out = (float*)d_out;
    float* out_nf = out + (size_t)2 * N * 3;          // ymax in-place in d_out

    float* wsf    = (float*)d_ws;
    float* fstats = wsf;                              // [512]
    float* part   = wsf + 512;                        // [1024*256]
    float* ymin   = part + (size_t)GRID_STATS * 256;  // [N*128]
    short* wbase  = (short*)(ymin + (size_t)N * 128);
    short* wf0h = wbase;               // 12*512
    short* wf0l = wf0h + 12 * 512;
    short* wf1h = wf0l + 12 * 512;     // 8*512
    short* wf1l = wf1h + 8 * 512;
    short* wf2h = wf1l + 8 * 512;      // 16*512
    short* wf2l = wf2h + 16 * 512;

    dim3 blk(256), grd(GRID_STATS);

    prep_weights<<<dim3(9), blk, 0, stream>>>(w0, w1, w2,
        wf0h, wf0l, wf1h, wf1l, wf2h, wf2l);

    stage_kernel<0><<<grd, blk, 0, stream>>>(center, normal, feature, gidx,
        wf0h, wf0l, wf1h, wf1l, wf2h, wf2l, b0, b1, b2,
        g0, be0, g1, be1, fstats, part, out_nf, ymin, ntiles, inv_cnt);
    reduce_partials<<<dim3(128), blk, 0, stream>>>(part, fstats, 0, GRID_STATS);

    stage_kernel<1><<<grd, blk, 0, stream>>>(center, normal, feature, gidx,
        wf0h, wf0l, wf1h, wf1l, wf2h, wf2l, b0, b1, b2,
        g0, be0, g1, be1, fstats, part, out_nf, ymin, ntiles, inv_cnt);
    reduce_partials<<<dim3(128), blk, 0, stream>>>(part, fstats, 128, GRID_STATS);

    stage_kernel<2><<<grd, blk, 0, stream>>>(center, normal, feature, gidx,
        wf0h, wf0l, wf1h, wf1l, wf2h, wf2l, b0, b1, b2,
        g0, be0, g1, be1, fstats, part, out_nf, ymin, ntiles, inv_cnt);
    reduce_partials<<<dim3(256), blk, 0, stream>>>(part, fstats, 256, GRID_STATS);

    int total = 2 * N * 3 + N * 128 + 1;
    final_kernel<<<dim3((total + 255) / 256), blk, 0, stream>>>(
        center, normal, offs, g2, be2, fstats, out_nf, ymin, out, N, inv_cnt);
}

// Round 4
// 297.165 us; speedup vs baseline: 6.9466x; 2.0099x over previous
//
#include <hip/hip_runtime.h>
#include <hip/hip_bf16.h>
#include <math.h>

// SurfaceAbstraction: gather(32 nbrs) -> [feat(64)|geom(9)|pad](K=96 permuted)
// -> 3x (1x1 conv + global-batch BN + relu) -> max over neighbors.
// R4: wave = output-channel slice (not point). 18 weight fragments (hi+lo
// bf16 split) live in registers for the whole kernel; no weight traffic in
// the tile loop. <=128 VGPR target -> 4 waves/SIMD. X1 in separate LDS
// buffer; X2 reuses Xs. Stats channels disjoint per wave -> no LDS reduce.

typedef __attribute__((ext_vector_type(8))) short short8;
typedef __attribute__((ext_vector_type(4))) float f32x4;

constexpr int NS = 32;
constexpr int GRID0  = 1024;   // stage0 blocks (32KB LDS -> 4/CU)
constexpr int GRID12 = 768;    // stage1/2 blocks (48KB LDS -> 3/CU)
constexpr float BN_EPS = 1e-5f;
constexpr float INV_PI  = 0.31830988618379067f;
constexpr float INV_2PI = 0.15915494309189535f;

__device__ __forceinline__ short cvt_bf16(float f) {
    unsigned u = __float_as_uint(f);
    u = (u + 0x7FFFu + ((u >> 16) & 1u)) >> 16;
    return (short)u;
}
__device__ __forceinline__ float bf16_to_f(short s) {
    return __uint_as_float(((unsigned)(unsigned short)s) << 16);
}

// Weight fragments: frag(kt,nt), lane l holds W[n=nt*16+(l&15)][k=kt*32+(l>>4)*8+j]
// hi/lo bf16 split (w ~= hi + lo). conv0 K permuted: knew<64 -> orig 9+knew
// (feat); 64..71 -> orig 0..7; 72 -> orig 8; 73..95 -> 0.
__global__ __launch_bounds__(256) void prep_weights(
    const float* __restrict__ w0, const float* __restrict__ w1,
    const float* __restrict__ w2,
    short* __restrict__ wf0h, short* __restrict__ wf0l,
    short* __restrict__ wf1h, short* __restrict__ wf1l,
    short* __restrict__ wf2h, short* __restrict__ wf2l)
{
    int i = blockIdx.x * 256 + threadIdx.x;
    int l = i & 63;
    int f = i >> 6;
    float vals[8];
    short *dh, *dl;
    if (f < 12) {                       // conv0: 3 kt x 4 nt
        int kt = f >> 2, nt = f & 3;
        int n = nt * 16 + (l & 15);
        int k0 = kt * 32 + (l >> 4) * 8;
        for (int j = 0; j < 8; ++j) {
            int kn = k0 + j;
            float v;
            if (kn < 64)       v = w0[n * 73 + 9 + kn];
            else if (kn < 72)  v = w0[n * 73 + (kn - 64)];
            else if (kn == 72) v = w0[n * 73 + 8];
            else v = 0.f;
            vals[j] = v;
        }
        dh = wf0h + (size_t)f * 512 + l * 8;
        dl = wf0l + (size_t)f * 512 + l * 8;
    } else if (f < 20) {                // conv1: 2 kt x 4 nt
        int ff = f - 12;
        int kt = ff >> 2, nt = ff & 3;
        int n = nt * 16 + (l & 15);
        int k0 = kt * 32 + (l >> 4) * 8;
        for (int j = 0; j < 8; ++j) vals[j] = w1[n * 64 + k0 + j];
        dh = wf1h + (size_t)ff * 512 + l * 8;
        dl = wf1l + (size_t)ff * 512 + l * 8;
    } else if (f < 36) {                // conv2: 2 kt x 8 nt
        int ff = f - 20;
        int kt = ff >> 3, nt = ff & 7;
        int n = nt * 16 + (l & 15);
        int k0 = kt * 32 + (l >> 4) * 8;
        for (int j = 0; j < 8; ++j) vals[j] = w2[n * 64 + k0 + j];
        dh = wf2h + (size_t)ff * 512 + l * 8;
        dl = wf2l + (size_t)ff * 512 + l * 8;
    } else return;
    for (int j = 0; j < 8; ++j) {
        short h = cvt_bf16(vals[j]);
        dh[j] = h;
        dl[j] = cvt_bf16(vals[j] - bf16_to_f(h));
    }
}

template <int STAGE>
__global__ __launch_bounds__(256, 4) void stage_kernel(
    const float* __restrict__ center, const float* __restrict__ normal,
    const float* __restrict__ feature, const int* __restrict__ gidx,
    const short* __restrict__ wf0h, const short* __restrict__ wf0l,
    const short* __restrict__ wf1h, const short* __restrict__ wf1l,
    const short* __restrict__ wf2h, const short* __restrict__ wf2l,
    const float* __restrict__ b0, const float* __restrict__ b1,
    const float* __restrict__ b2,
    const float* __restrict__ g0, const float* __restrict__ be0,
    const float* __restrict__ g1, const float* __restrict__ be1,
    const float* __restrict__ fstats, float* __restrict__ part,
    float* __restrict__ ymax, float* __restrict__ ymin,
    int ntiles, float inv_cnt)
{
    // Xs: 128 rows x 16 units(16B), swizzle: unit u of row r at u^(r&7)
    __shared__ __align__(16) short Xs[128 * 128];
    __shared__ __align__(16) short X1s[(STAGE >= 1) ? 128 * 64 : 16];

    const int t    = threadIdx.x;
    const int lane = t & 63;
    const int wv   = __builtin_amdgcn_readfirstlane(t >> 6);
    const int ln   = lane & 15;
    const int kg   = lane >> 4;
    const int rs   = ln & 7;            // row&7 for this lane's A-rows
    const int chW  = wv * 16 + ln;      // write channel for conv0/conv1

    // ---- weight fragments -> registers (persistent, loaded once) ----
    short8 W0h[3], W0l[3];
#pragma unroll
    for (int kt = 0; kt < 3; ++kt) {
        W0h[kt] = *(const short8*)(wf0h + (size_t)((kt*4 + wv) * 64 + lane) * 8);
        W0l[kt] = *(const short8*)(wf0l + (size_t)((kt*4 + wv) * 64 + lane) * 8);
    }
    short8 W1h[2], W1l[2];
    if constexpr (STAGE >= 1) {
#pragma unroll
        for (int kt = 0; kt < 2; ++kt) {
            W1h[kt] = *(const short8*)(wf1h + (size_t)((kt*4 + wv) * 64 + lane) * 8);
            W1l[kt] = *(const short8*)(wf1l + (size_t)((kt*4 + wv) * 64 + lane) * 8);
        }
    }
    short8 W2h[2][2], W2l[2][2];        // [nti][kt]
    if constexpr (STAGE == 2) {
#pragma unroll
        for (int nti = 0; nti < 2; ++nti)
#pragma unroll
            for (int kt = 0; kt < 2; ++kt) {
                int ff = kt * 8 + (wv * 2 + nti);
                W2h[nti][kt] = *(const short8*)(wf2h + (size_t)(ff * 64 + lane) * 8);
                W2l[nti][kt] = *(const short8*)(wf2l + (size_t)(ff * 64 + lane) * 8);
            }
    }

    // ---- per-lane BN consts + biases (channel fixed per lane) ----
    const float bb0 = b0[chW];
    float bb1 = 0.f, bb2a = 0.f, bb2b = 0.f;
    float a0v = 0.f, c0v = 0.f, a1v = 0.f, c1v = 0.f;
    if constexpr (STAGE >= 1) {
        bb1 = b1[chW];
        float mean = fstats[chW] * inv_cnt;
        float var  = fstats[64 + chW] * inv_cnt - mean * mean;
        a0v = g0[chW] * rsqrtf(fmaxf(var, 0.f) + BN_EPS);
        c0v = be0[chW] - a0v * mean;
    }
    if constexpr (STAGE == 2) {
        bb2a = b2[wv * 32 + ln];
        bb2b = b2[wv * 32 + 16 + ln];
        float mean = fstats[128 + chW] * inv_cnt;
        float var  = fstats[192 + chW] * inv_cnt - mean * mean;
        a1v = g1[chW] * rsqrtf(fmaxf(var, 0.f) + BN_EPS);
        c1v = be1[chW] - a1v * mean;
    }

    {   // zero pad units 10,11 (k 80..95) once; never overwritten
        int r = t >> 1, u = 10 + (t & 1);
        short8 z; z[0]=0;z[1]=0;z[2]=0;z[3]=0;z[4]=0;z[5]=0;z[6]=0;z[7]=0;
        *(short8*)(Xs + r * 128 + ((u ^ (r & 7)) * 8)) = z;
    }

    constexpr int NT = (STAGE == 2) ? 2 : 1;
    float ssum[NT], ssq[NT];
#pragma unroll
    for (int nt = 0; nt < NT; ++nt) { ssum[nt] = 0.f; ssq[nt] = 0.f; }

    for (int tile = blockIdx.x; tile < ntiles; tile += gridDim.x) {
        const int m0 = tile * 4;
        __syncthreads();               // prior tile's LDS reads done
        {   // ---- gather: 128 samples, 2 threads/sample ----
            const int s = t & 127, h = t >> 7;
            const int m = m0 + (s >> 5);
            const int j = gidx[m * NS + (s & 31)];
            short* xr = Xs + s * 128;
            const int rx = (s & 7) * 8;
            const float4* fp = (const float4*)(feature + (size_t)j * 64 + h * 32);
#pragma unroll
            for (int q = 0; q < 4; ++q) {
                float4 a = fp[2 * q], b = fp[2 * q + 1];
                short8 v;
                v[0]=cvt_bf16(a.x); v[1]=cvt_bf16(a.y); v[2]=cvt_bf16(a.z); v[3]=cvt_bf16(a.w);
                v[4]=cvt_bf16(b.x); v[5]=cvt_bf16(b.y); v[6]=cvt_bf16(b.z); v[7]=cvt_bf16(b.w);
                *(short8*)(xr + ((((h * 4 + q) * 8)) ^ rx)) = v;
            }
            if (h == 0) {
                float gx = center[j*3+0] - center[m*3+0];
                float gy = center[j*3+1] - center[m*3+1];
                float gz = center[j*3+2] - center[m*3+2];
                float rho = sqrtf(gx*gx + gy*gy + gz*gz);
                float th = 0.f;
                if (rho > 0.f) th = acosf(fminf(1.f, fmaxf(-1.f, gz / rho))) * INV_PI;
                float ph = atan2f(gy, gx) * INV_2PI + 0.5f;
                short8 v;
                v[0]=cvt_bf16(gx);  v[1]=cvt_bf16(gy); v[2]=cvt_bf16(gz);
                v[3]=cvt_bf16(rho); v[4]=cvt_bf16(th); v[5]=cvt_bf16(ph);
                v[6]=cvt_bf16(normal[j*3+0]); v[7]=cvt_bf16(normal[j*3+1]);
                *(short8*)(xr + ((8 * 8) ^ rx)) = v;
            } else {
                short8 v; v[0]=cvt_bf16(normal[j*3+2]);
                v[1]=0;v[2]=0;v[3]=0;v[4]=0;v[5]=0;v[6]=0;v[7]=0;
                *(short8*)(xr + ((9 * 8) ^ rx)) = v;
            }
        }
        __syncthreads();
        // ---- conv0: wave's 16 cols x all 8 m-tiles, K=96 ----
#pragma unroll 2
        for (int mt = 0; mt < 8; ++mt) {
            const short* arow = Xs + (mt * 16 + ln) * 128;
            f32x4 acc = {bb0, bb0, bb0, bb0};
#pragma unroll
            for (int kt = 0; kt < 3; ++kt) {
                short8 A = *(const short8*)(arow + (((kt*4 + kg) ^ rs) * 8));
                acc = __builtin_amdgcn_mfma_f32_16x16x32_bf16(A, W0h[kt], acc, 0, 0, 0);
                acc = __builtin_amdgcn_mfma_f32_16x16x32_bf16(A, W0l[kt], acc, 0, 0, 0);
            }
            if constexpr (STAGE == 0) {
#pragma unroll
                for (int r = 0; r < 4; ++r) {
                    float y = acc[r];
                    ssum[0] += y; ssq[0] += y * y;
                }
            } else {
#pragma unroll
                for (int r = 0; r < 4; ++r) {
                    int row = mt * 16 + kg * 4 + r;
                    float x1 = fmaxf(a0v * acc[r] + c0v, 0.f);
                    X1s[row * 64 + ((((chW >> 3) ^ (row & 7)) << 3) | (chW & 7))] = cvt_bf16(x1);
                }
            }
        }
        if constexpr (STAGE >= 1) {
            __syncthreads();           // X1 complete
            // ---- conv1: K=64, X1s -> (stats | X2 in Xs units 0..7) ----
#pragma unroll 2
            for (int mt = 0; mt < 8; ++mt) {
                const short* arow = X1s + (mt * 16 + ln) * 64;
                f32x4 acc = {bb1, bb1, bb1, bb1};
#pragma unroll
                for (int kt = 0; kt < 2; ++kt) {
                    short8 A = *(const short8*)(arow + (((kt*4 + kg) ^ rs) * 8));
                    acc = __builtin_amdgcn_mfma_f32_16x16x32_bf16(A, W1h[kt], acc, 0, 0, 0);
                    acc = __builtin_amdgcn_mfma_f32_16x16x32_bf16(A, W1l[kt], acc, 0, 0, 0);
                }
                if constexpr (STAGE == 1) {
#pragma unroll
                    for (int r = 0; r < 4; ++r) {
                        float y = acc[r];
                        ssum[0] += y; ssq[0] += y * y;
                    }
                } else {
#pragma unroll
                    for (int r = 0; r < 4; ++r) {
                        int row = mt * 16 + kg * 4 + r;
                        float x2 = fmaxf(a1v * acc[r] + c1v, 0.f);
                        Xs[row * 128 + ((((chW >> 3) ^ (row & 7)) << 3) | (chW & 7))] = cvt_bf16(x2);
                    }
                }
            }
        }
        if constexpr (STAGE == 2) {
            __syncthreads();           // X2 complete
            // ---- conv2: wave's 32 cols, 4 points, stats + max/min ----
#pragma unroll
            for (int p = 0; p < 4; ++p) {
                float mx0 = -3.402823466e38f, mn0 = 3.402823466e38f;
                float mx1 = -3.402823466e38f, mn1 = 3.402823466e38f;
#pragma unroll
                for (int mh = 0; mh < 2; ++mh) {
                    const int mt = p * 2 + mh;
                    const short* arow = Xs + (mt * 16 + ln) * 128;
                    short8 A0 = *(const short8*)(arow + (((kg)     ^ rs) * 8));
                    short8 A1 = *(const short8*)(arow + (((4 + kg) ^ rs) * 8));
                    f32x4 acc = {bb2a, bb2a, bb2a, bb2a};
                    acc = __builtin_amdgcn_mfma_f32_16x16x32_bf16(A0, W2h[0][0], acc, 0, 0, 0);
                    acc = __builtin_amdgcn_mfma_f32_16x16x32_bf16(A0, W2l[0][0], acc, 0, 0, 0);
                    acc = __builtin_amdgcn_mfma_f32_16x16x32_bf16(A1, W2h[0][1], acc, 0, 0, 0);
                    acc = __builtin_amdgcn_mfma_f32_16x16x32_bf16(A1, W2l[0][1], acc, 0, 0, 0);
#pragma unroll
                    for (int r = 0; r < 4; ++r) {
                        float y = acc[r];
                        ssum[0] += y; ssq[0] += y * y;
                        mx0 = fmaxf(mx0, y); mn0 = fminf(mn0, y);
                    }
                    f32x4 acd = {bb2b, bb2b, bb2b, bb2b};
                    acd = __builtin_amdgcn_mfma_f32_16x16x32_bf16(A0, W2h[1][0], acd, 0, 0, 0);
                    acd = __builtin_amdgcn_mfma_f32_16x16x32_bf16(A0, W2l[1][0], acd, 0, 0, 0);
                    acd = __builtin_amdgcn_mfma_f32_16x16x32_bf16(A1, W2h[1][1], acd, 0, 0, 0);
                    acd = __builtin_amdgcn_mfma_f32_16x16x32_bf16(A1, W2l[1][1], acd, 0, 0, 0);
#pragma unroll
                    for (int r = 0; r < 4; ++r) {
                        float y = acd[r];
                        ssum[1] += y; ssq[1] += y * y;
                        mx1 = fmaxf(mx1, y); mn1 = fminf(mn1, y);
                    }
                }
                mx0 = fmaxf(mx0, __shfl_xor(mx0, 16)); mn0 = fminf(mn0, __shfl_xor(mn0, 16));
                mx0 = fmaxf(mx0, __shfl_xor(mx0, 32)); mn0 = fminf(mn0, __shfl_xor(mn0, 32));
                mx1 = fmaxf(mx1, __shfl_xor(mx1, 16)); mn1 = fminf(mn1, __shfl_xor(mn1, 16));
                mx1 = fmaxf(mx1, __shfl_xor(mx1, 32)); mn1 = fminf(mn1, __shfl_xor(mn1, 32));
                if (lane < 16) {
                    size_t base = (size_t)(m0 + p) * 128 + wv * 32 + ln;
                    ymax[base]      = mx0; ymin[base]      = mn0;
                    ymax[base + 16] = mx1; ymin[base + 16] = mn1;
                }
            }
        }
    }

    // ---- stats epilogue: channels disjoint per wave -> direct write ----
    float* pb = part + (size_t)blockIdx.x * 256;
#pragma unroll
    for (int nt = 0; nt < NT; ++nt) {
        float v = ssum[nt], q = ssq[nt];
        v += __shfl_xor(v, 16); q += __shfl_xor(q, 16);
        v += __shfl_xor(v, 32); q += __shfl_xor(q, 32);
        if (lane < 16) {
            constexpr int NCH = (STAGE == 2) ? 128 : 64;
            int c = (STAGE == 2) ? (wv * 32 + nt * 16 + ln) : (wv * 16 + ln);
            pb[c] = v; pb[NCH + c] = q;
        }
    }
}

__global__ __launch_bounds__(256) void reduce_partials(
    const float* __restrict__ part, float* __restrict__ fstats,
    int base, int nblocks)
{
    __shared__ float red[256];
    int c = blockIdx.x;
    float s = 0.f;
    for (int b = threadIdx.x; b < nblocks; b += 256)
        s += part[(size_t)b * 256 + c];
    red[threadIdx.x] = s;
    __syncthreads();
    for (int off = 128; off > 0; off >>= 1) {
        if (threadIdx.x < off) red[threadIdx.x] += red[threadIdx.x + off];
        __syncthreads();
    }
    if (threadIdx.x == 0) fstats[base + c] = red[0];
}

__global__ __launch_bounds__(256) void final_kernel(
    const float* __restrict__ center, const float* __restrict__ normal,
    const int* __restrict__ offs,
    const float* __restrict__ g2, const float* __restrict__ be2,
    const float* __restrict__ fstats,
    const float* __restrict__ ymax, const float* __restrict__ ymin,
    float* __restrict__ out, int N, float inv_cnt)
{
    int i = blockIdx.x * 256 + threadIdx.x;
    int nc = N * 3;
    int nf = N * 128;
    int total = 2 * nc + nf + 1;
    if (i >= total) return;
    if (i < nc) {
        out[i] = center[i];
    } else if (i < 2 * nc) {
        out[i] = normal[i - nc];
    } else if (i < 2 * nc + nf) {
        int idx = i - 2 * nc;
        int c = idx & 127;
        float mean = fstats[256 + c] * inv_cnt;
        float var  = fstats[384 + c] * inv_cnt - mean * mean;
        float a = g2[c] * rsqrtf(fmaxf(var, 0.f) + BN_EPS);
        float v = (a >= 0.f) ? ymax[idx] : ymin[idx];   // monotone BN+relu
        out[i] = fmaxf(a * (v - mean) + be2[c], 0.f);
    } else {
        out[i] = (float)offs[0];
    }
}

extern "C" void kernel_launch(void* const* d_in, const int* in_sizes, int n_in,
                              void* d_out, int out_size, void* d_ws, size_t ws_size,
                              hipStream_t stream)
{
    const float* center  = (const float*)d_in[0];
    const float* normal  = (const float*)d_in[1];
    const float* feature = (const float*)d_in[2];
    const int*   offs    = (const int*)d_in[3];
    const int*   gidx    = (const int*)d_in[4];
    const float* w0  = (const float*)d_in[5];
    const float* b0  = (const float*)d_in[6];
    const float* g0  = (const float*)d_in[7];
    const float* be0 = (const float*)d_in[8];
    const float* w1  = (const float*)d_in[9];
    const float* b1  = (const float*)d_in[10];
    const float* g1  = (const float*)d_in[11];
    const float* be1 = (const float*)d_in[12];
    const float* w2  = (const float*)d_in[13];
    const float* b2  = (const float*)d_in[14];
    const float* g2  = (const float*)d_in[15];
    const float* be2 = (const float*)d_in[16];

    const int N = in_sizes[0] / 3;
    const int ntiles = N / 4;
    const float inv_cnt = 1.0f / (float)((size_t)N * NS);

    float* out = (float*)d_out;
    float* out_nf = out + (size_t)2 * N * 3;          // ymax in-place in d_out

    float* wsf    = (float*)d_ws;
    float* fstats = wsf;                              // [512]
    float* part   = wsf + 512;                        // [1024*256]
    float* ymin   = part + (size_t)1024 * 256;        // [N*128]
    short* wbase  = (short*)(ymin + (size_t)N * 128);
    short* wf0h = wbase;               // 12*512
    short* wf0l = wf0h + 12 * 512;
    short* wf1h = wf0l + 12 * 512;     // 8*512
    short* wf1l = wf1h + 8 * 512;
    short* wf2h = wf1l + 8 * 512;      // 16*512
    short* wf2l = wf2h + 16 * 512;

    dim3 blk(256);

    prep_weights<<<dim3(9), blk, 0, stream>>>(w0, w1, w2,
        wf0h, wf0l, wf1h, wf1l, wf2h, wf2l);

    stage_kernel<0><<<dim3(GRID0), blk, 0, stream>>>(center, normal, feature, gidx,
        wf0h, wf0l, wf1h, wf1l, wf2h, wf2l, b0, b1, b2,
        g0, be0, g1, be1, fstats, part, out_nf, ymin, ntiles, inv_cnt);
    reduce_partials<<<dim3(128), blk, 0, stream>>>(part, fstats, 0, GRID0);

    stage_kernel<1><<<dim3(GRID12), blk, 0, stream>>>(center, normal, feature, gidx,
        wf0h, wf0l, wf1h, wf1l, wf2h, wf2l, b0, b1, b2,
        g0, be0, g1, be1, fstats, part, out_nf, ymin, ntiles, inv_cnt);
    reduce_partials<<<dim3(128), blk, 0, stream>>>(part, fstats, 128, GRID12);

    stage_kernel<2><<<dim3(GRID12), blk, 0, stream>>>(center, normal, feature, gidx,
        wf0h, wf0l, wf1h, wf1l, wf2h, wf2l, b0, b1, b2,
        g0, be0, g1, be1, fstats, part, out_nf, ymin, ntiles, inv_cnt);
    reduce_partials<<<dim3(256), blk, 0, stream>>>(part, fstats, 256, GRID12);

    int total = 2 * N * 3 + N * 128 + 1;
    final_kernel<<<dim3((total + 255) / 256), blk, 0, stream>>>(
        center, normal, offs, g2, be2, fstats, out_nf, ymin, out, N, inv_cnt);
}